// Round 1
// baseline (1273.523 us; speedup 1.0000x reference)
//
#include <hip/hip_runtime.h>
#include <hip/hip_bf16.h>
#include <math.h>

#define T_   64
#define B_   2048
#define OBS_ 48
#define H_   256
#define M1_  512
#define M2_  256
#define A_   12
#define BH_  (B_ * H_)
#define KP_  320   // padded K for scan: 64 (x, padded from 48) + 256 (h)
#define R_   16    // batch rows per persistent block
#define NBLK_ (B_ / R_)   // 128

typedef unsigned short u16;
typedef __attribute__((ext_vector_type(8))) short bf16x8;
typedef __attribute__((ext_vector_type(4))) float f32x4;

static __device__ __forceinline__ u16 f2b(float f) {
    __hip_bfloat16 h = __float2bfloat16(f);
    return *reinterpret_cast<u16*>(&h);
}
static __device__ __forceinline__ float b2f(u16 u) {
    union { unsigned u32v; float f; } v; v.u32v = ((unsigned)u) << 16; return v.f;
}
static __device__ __forceinline__ float sigm(float x) {
    return 1.0f / (1.0f + __expf(-x));
}
static __device__ __forceinline__ float tanh_fast(float x) {
    x = fminf(fmaxf(x, -15.0f), 15.0f);
    float e = __expf(2.0f * x);
    return (e - 1.0f) / (e + 1.0f);
}
static __device__ __forceinline__ float elu(float x) {
    return x > 0.0f ? x : (__expf(x) - 1.0f);
}

// ---------------------------------------------------------------------------
// Pre-pass kernels
// ---------------------------------------------------------------------------
__global__ void prep_xpad(const float* __restrict__ x, u16* __restrict__ xpad) {
    const int gid = blockIdx.x * 256 + threadIdx.x;   // T*B*8 threads
    const int r = gid >> 3, k0 = (gid & 7) * 8;
    u16 tmp[8];
    if (k0 < OBS_) {
        const float4 f0 = *(const float4*)(x + (size_t)r * OBS_ + k0);
        const float4 f1 = *(const float4*)(x + (size_t)r * OBS_ + k0 + 4);
        tmp[0] = f2b(f0.x); tmp[1] = f2b(f0.y); tmp[2] = f2b(f0.z); tmp[3] = f2b(f0.w);
        tmp[4] = f2b(f1.x); tmp[5] = f2b(f1.y); tmp[6] = f2b(f1.z); tmp[7] = f2b(f1.w);
    } else {
        #pragma unroll
        for (int i = 0; i < 8; ++i) tmp[i] = 0;
    }
    *(uint4*)(xpad + (size_t)gid * 8) = *(uint4*)tmp;
}

// Wcat row layout is PERMUTED for the persistent LSTM kernel:
//   out-row n_p = wave*128 + gate*32 + jj  <-  src-row gate*256 + wave*32 + jj
// so each wave's 128-column slice holds all 4 gates for the same 32 hidden
// units -> gate fusion is lane-local (no LDS exchange).
__global__ void prep_weights(const float* __restrict__ W_ih, const float* __restrict__ W_hh,
                             const float* __restrict__ W1,  const float* __restrict__ W2,
                             const float* __restrict__ Wm,  const float* __restrict__ Ws,
                             u16* __restrict__ Wcat, u16* __restrict__ W1T,
                             u16* __restrict__ W2T,  u16* __restrict__ WhT) {
    const int b = blockIdx.x, tid = threadIdx.x;
    if (b < 1024) {
        const int w = b >> 7, rem = b & 127, gate = rem >> 5, jj = rem & 31;
        const int src = gate * 256 + w * 32 + jj;
        for (int k = tid; k < KP_; k += 256) {
            float v;
            if (k < OBS_)    v = W_ih[src * OBS_ + k];
            else if (k < 64) v = 0.0f;
            else             v = W_hh[src * H_ + (k - 64)];
            Wcat[b * KP_ + k] = f2b(v);
        }
    } else if (b < 1536) {
        const int n = b - 1024;                       // W1T [512][256]
        W1T[n * 256 + tid] = f2b(W1[tid * M1_ + n]);
    } else if (b < 1792) {
        const int n = b - 1536;                       // W2T [256][512]
        W2T[n * 512 + tid]       = f2b(W2[tid * M2_ + n]);
        W2T[n * 512 + tid + 256] = f2b(W2[(tid + 256) * M2_ + n]);
    } else {
        const int n = b - 1792;                       // WhT [32][256]
        float v = 0.0f;
        if (n < 12)                 v = Wm[tid * A_ + n];
        else if (n >= 16 && n < 28) v = Ws[tid * A_ + (n - 16)];
        WhT[n * 256 + tid] = f2b(v);
    }
}

// ---------------------------------------------------------------------------
// Persistent LSTM scan. The recurrence is batch-row independent, so each
// block owns 16 rows and runs all 64 timesteps with NO inter-block sync:
//  - h, c state live in registers / LDS (no Hin/Hout/Cst global round-trip)
//  - weights are streamed from (XCD-resident) L2 each step; the last 2 of
//    10 K-fragments are register-stationary across all steps (-20% traffic)
//  - per-step cost: 2 in-block barriers, 64 global dwordx4 weight loads/lane
// A-tile (LDS): [16 rows][320 K] bf16, XOR-swizzled in 8-elem chunks.
// ---------------------------------------------------------------------------
#define ASM16_(row, chunk) (a_sm + (size_t)(row) * 320 + (size_t)((((chunk) ^ ((row) & 7))) << 3))

__global__ __launch_bounds__(512, 2) void lstm_persist(
    const u16*  __restrict__ xpad,   // [T][B][64] bf16
    const int*  __restrict__ done,   // [T][B]
    const float* __restrict__ h0,    // [B][256] fp32
    const float* __restrict__ c0,    // [B][256] fp32
    u16*        __restrict__ hs,     // [T+1][B][256] bf16; we write slices 1..T
    const u16*  __restrict__ Wcat,   // [1024 permuted][320] bf16
    const float* __restrict__ b_ih,
    const float* __restrict__ b_hh)
{
    __shared__ u16 a_sm[R_ * 320];   // 10 KB

    const int tid  = threadIdx.x;
    const int lane = tid & 63;
    const int wave = tid >> 6;               // 0..7: owns hidden cols [wave*32, wave*32+32)
    const int quad = lane >> 4, l16 = lane & 15;
    const int b0 = blockIdx.x * R_;

    // ---- per-lane constants: fused biases for this lane's 8 (gate, jh) slots
    float bsum[4][2];
    #pragma unroll
    for (int g = 0; g < 4; ++g)
        #pragma unroll
        for (int jh = 0; jh < 2; ++jh) {
            const int j = wave * 32 + jh * 16 + l16;
            bsum[g][jh] = b_ih[g * 256 + j] + b_hh[g * 256 + j];
        }

    // ---- persistent c state: rows quad*4+r, cols wave*32 + jh*16 + l16
    float cst[4][2];
    #pragma unroll
    for (int r = 0; r < 4; ++r) {
        const int row = quad * 4 + r;
        const float kp = done[b0 + row] ? 0.0f : 1.0f;     // done[0][...]
        #pragma unroll
        for (int jh = 0; jh < 2; ++jh) {
            const int j = wave * 32 + jh * 16 + l16;
            cst[r][jh] = c0[(size_t)(b0 + row) * H_ + j] * kp;
        }
    }

    // ---- register-stationary B fragments for kt = 8, 9 (64 VGPRs)
    const u16* wb = Wcat + (size_t)(wave * 128 + l16) * KP_ + quad * 8;
    bf16x8 Bs[8][2];
    #pragma unroll
    for (int nf = 0; nf < 8; ++nf)
        #pragma unroll
        for (int ks = 0; ks < 2; ++ks)
            Bs[nf][ks] = *(const bf16x8*)(wb + (size_t)nf * 16 * KP_ + (8 + ks) * 32);

    // ---- init A-tile: x(0) | h0 * keep(0)
    if (tid < 128) {
        const int row = tid >> 3, seg = tid & 7;
        *(uint4*)ASM16_(row, seg) = *(const uint4*)(xpad + (size_t)(b0 + row) * 64 + seg * 8);
    }
    #pragma unroll
    for (int r = 0; r < 4; ++r) {
        const int row = quad * 4 + r;
        const float kp = done[b0 + row] ? 0.0f : 1.0f;
        #pragma unroll
        for (int jh = 0; jh < 2; ++jh) {
            const int j = wave * 32 + jh * 16 + l16;
            const int e = 64 + j;
            *(ASM16_(row, e >> 3) + (e & 7)) = f2b(h0[(size_t)(b0 + row) * H_ + j] * kp);
        }
    }
    __syncthreads();

    // ================= 64-step scan, zero grid syncs =================
    for (int t = 0; t < T_; ++t) {
        // ---- GEMM: [16 rows] x [K=320] x [128 cols/wave]; 80 MFMA/wave
        f32x4 acc[8];
        #pragma unroll
        for (int nf = 0; nf < 8; ++nf) acc[nf] = (f32x4){0, 0, 0, 0};

        #pragma unroll
        for (int kt = 0; kt < 8; ++kt) {
            const bf16x8 af = *(const bf16x8*)ASM16_(l16, kt * 4 + quad);
            #pragma unroll
            for (int nf = 0; nf < 8; ++nf) {
                const bf16x8 bw = *(const bf16x8*)(wb + (size_t)nf * 16 * KP_ + kt * 32);
                acc[nf] = __builtin_amdgcn_mfma_f32_16x16x32_bf16(af, bw, acc[nf], 0, 0, 0);
            }
        }
        #pragma unroll
        for (int ks = 0; ks < 2; ++ks) {
            const bf16x8 af = *(const bf16x8*)ASM16_(l16, (8 + ks) * 4 + quad);
            #pragma unroll
            for (int nf = 0; nf < 8; ++nf)
                acc[nf] = __builtin_amdgcn_mfma_f32_16x16x32_bf16(af, Bs[nf][ks], acc[nf], 0, 0, 0);
        }
        __syncthreads();   // all waves done reading A-tile

        // ---- stage x(t+1) into A-tile x-region (disjoint from h-region)
        if (t + 1 < T_ && tid < 128) {
            const int row = tid >> 3, seg = tid & 7;
            *(uint4*)ASM16_(row, seg) =
                *(const uint4*)(xpad + (size_t)((t + 1) * B_ + b0 + row) * 64 + seg * 8);
        }

        // ---- epilogue: lane-local gate fusion (permuted Wcat layout)
        //      nf = gate*2 + jh  ->  gi=acc[jh], gf=acc[2+jh], gg=acc[4+jh], go=acc[6+jh]
        u16* hsrow = hs + (size_t)(t + 1) * BH_;
        #pragma unroll
        for (int r = 0; r < 4; ++r) {
            const int row = quad * 4 + r;
            const float kp = (t + 1 < T_) ? (done[(size_t)(t + 1) * B_ + b0 + row] ? 0.0f : 1.0f)
                                          : 1.0f;
            #pragma unroll
            for (int jh = 0; jh < 2; ++jh) {
                const float gi = acc[0 + jh][r] + bsum[0][jh];
                const float gf = acc[2 + jh][r] + bsum[1][jh];
                const float gg = acc[4 + jh][r] + bsum[2][jh];
                const float go = acc[6 + jh][r] + bsum[3][jh];
                const float cn = sigm(gf) * cst[r][jh] + sigm(gi) * tanh_fast(gg);
                const float h  = sigm(go) * tanh_fast(cn);
                cst[r][jh] = cn * kp;                       // pre-mask c for step t+1
                const int j = wave * 32 + jh * 16 + l16;
                hsrow[(size_t)(b0 + row) * H_ + j] = f2b(h);      // unmasked history
                const int e = 64 + j;
                *(ASM16_(row, e >> 3) + (e & 7)) = f2b(h * kp);   // masked h for t+1 GEMM
            }
        }
        __syncthreads();   // A-tile (x + h) ready for next step
    }
}

// ---------------------------------------------------------------------------
// MLP v2 (unchanged, proven): 64 rows/block, 512 threads, two-phase y1.
// ---------------------------------------------------------------------------
#define SY(row, col) ((size_t)(row) * 256 + ((((col) >> 3) ^ ((row) & 7)) << 3) + ((col) & 7))

__global__ __launch_bounds__(512, 4) void mlp_mfma64(
    const u16*  __restrict__ hs,    // [nrows][256] bf16
    float*      __restrict__ out,   // [nrows][14]
    const float* __restrict__ lng, const float* __restrict__ lnb,
    const u16*  __restrict__ W1T, const float* __restrict__ b1,
    const u16*  __restrict__ W2T, const float* __restrict__ b2,
    const u16*  __restrict__ WhT,
    const float* __restrict__ bm, const float* __restrict__ bs)
{
    __shared__ u16 ybf[64 * 256];   // 32 KB swizzled: LN output, later y2
    __shared__ u16 yh [64 * 256];   // 32 KB swizzled: y1 column-half; later ls overlay

    const int tid  = threadIdx.x;
    const int lane = tid & 63;
    const int wave = tid >> 6;        // 0..7
    const int quad = lane >> 4, l16 = lane & 15;
    const int row0 = blockIdx.x * 64;

    // ---- LayerNorm: wave w -> rows w*8..w*8+7; lane holds 4 cols ----
    {
        const float4 gv = *(const float4*)(lng + lane * 4);
        const float4 bv = *(const float4*)(lnb + lane * 4);
        #pragma unroll
        for (int rr = 0; rr < 8; ++rr) {
            const int r = wave * 8 + rr;
            const ushort4 hv = *(const ushort4*)(hs + (size_t)(row0 + r) * H_ + lane * 4);
            const float v0 = b2f(hv.x), v1 = b2f(hv.y), v2 = b2f(hv.z), v3 = b2f(hv.w);
            float s  = v0 + v1 + v2 + v3;
            float ss = v0 * v0 + v1 * v1 + v2 * v2 + v3 * v3;
            #pragma unroll
            for (int off = 32; off > 0; off >>= 1) {
                s  += __shfl_down(s,  off);
                ss += __shfl_down(ss, off);
            }
            s = __shfl(s, 0); ss = __shfl(ss, 0);
            const float mu   = s * (1.0f / 256.0f);
            const float rstd = rsqrtf(ss * (1.0f / 256.0f) - mu * mu + 1e-5f);
            ushort4 o;
            o.x = f2b((v0 - mu) * rstd * gv.x + bv.x);
            o.y = f2b((v1 - mu) * rstd * gv.y + bv.y);
            o.z = f2b((v2 - mu) * rstd * gv.z + bv.z);
            o.w = f2b((v3 - mu) * rstd * gv.w + bv.w);
            *(ushort4*)(ybf + SY(r, lane * 4)) = o;
        }
    }
    __syncthreads();

    // ---- L2 partial accumulators: live across both phases ----
    f32x4 acc2[4][2];
    #pragma unroll
    for (int m = 0; m < 4; ++m)
        #pragma unroll
        for (int j = 0; j < 2; ++j) acc2[m][j] = (f32x4){0,0,0,0};

    #pragma unroll
    for (int ph = 0; ph < 2; ++ph) {
        // ---- L1 phase: y1 cols [ph*256, ph*256+256); wave n-slice 32 cols ----
        {
            f32x4 acc[4][2];
            #pragma unroll
            for (int m = 0; m < 4; ++m)
                #pragma unroll
                for (int j = 0; j < 2; ++j) acc[m][j] = (f32x4){0,0,0,0};
            const int n0 = ph * 256 + wave * 32;
            const u16* wp0 = W1T + (size_t)(n0 + l16) * 256 + quad * 8;
            const u16* wp1 = W1T + (size_t)(n0 + 16 + l16) * 256 + quad * 8;
            #pragma unroll
            for (int kt = 0; kt < 8; ++kt) {
                const int k0 = kt * 32;
                const bf16x8 bw0 = *(const bf16x8*)(wp0 + k0);
                const bf16x8 bw1 = *(const bf16x8*)(wp1 + k0);
                #pragma unroll
                for (int m = 0; m < 4; ++m) {
                    const bf16x8 af = *(const bf16x8*)(ybf + SY(m * 16 + l16, k0 + quad * 8));
                    acc[m][0] = __builtin_amdgcn_mfma_f32_16x16x32_bf16(af, bw0, acc[m][0], 0, 0, 0);
                    acc[m][1] = __builtin_amdgcn_mfma_f32_16x16x32_bf16(af, bw1, acc[m][1], 0, 0, 0);
                }
            }
            const float bb0 = b1[n0 + l16], bb1 = b1[n0 + 16 + l16];
            __syncthreads();   // yh free (prev phase consumed / first use)
            #pragma unroll
            for (int m = 0; m < 4; ++m)
                #pragma unroll
                for (int r = 0; r < 4; ++r) {
                    const int row = m * 16 + quad * 4 + r;
                    yh[SY(row, wave * 32 + l16)]      = f2b(elu(acc[m][0][r] + bb0));
                    yh[SY(row, wave * 32 + 16 + l16)] = f2b(elu(acc[m][1][r] + bb1));
                }
        }
        __syncthreads();

        // ---- L2 partial: K in [ph*256, ph*256+256); wave n-slice 32 cols ----
        {
            const int n0 = wave * 32;
            const u16* wp0 = W2T + (size_t)(n0 + l16) * 512 + ph * 256 + quad * 8;
            const u16* wp1 = W2T + (size_t)(n0 + 16 + l16) * 512 + ph * 256 + quad * 8;
            #pragma unroll
            for (int kt = 0; kt < 8; ++kt) {
                const int k0 = kt * 32;
                const bf16x8 bw0 = *(const bf16x8*)(wp0 + k0);
                const bf16x8 bw1 = *(const bf16x8*)(wp1 + k0);
                #pragma unroll
                for (int m = 0; m < 4; ++m) {
                    const bf16x8 af = *(const bf16x8*)(yh + SY(m * 16 + l16, k0 + quad * 8));
                    acc2[m][0] = __builtin_amdgcn_mfma_f32_16x16x32_bf16(af, bw0, acc2[m][0], 0, 0, 0);
                    acc2[m][1] = __builtin_amdgcn_mfma_f32_16x16x32_bf16(af, bw1, acc2[m][1], 0, 0, 0);
                }
            }
        }
        __syncthreads();
    }

    // ---- y2 = elu(acc2 + b2) -> ybf (LN data fully consumed) ----
    {
        const float bb0 = b2[wave * 32 + l16], bb1 = b2[wave * 32 + 16 + l16];
        #pragma unroll
        for (int m = 0; m < 4; ++m)
            #pragma unroll
            for (int r = 0; r < 4; ++r) {
                const int row = m * 16 + quad * 4 + r;
                ybf[SY(row, wave * 32 + l16)]      = f2b(elu(acc2[m][0][r] + bb0));
                ybf[SY(row, wave * 32 + 16 + l16)] = f2b(elu(acc2[m][1][r] + bb1));
            }
    }
    __syncthreads();

    // ---- Heads: waves 0..3 -> m-frag = wave; j=0 mean, j=1 logstd ----
    float* lsf = (float*)yh;   // overlay: [64][16] floats (yh free)
    if (wave < 4) {
        f32x4 a0 = {0,0,0,0}, a1 = {0,0,0,0};
        const u16* wp0 = WhT + (size_t)l16 * 256 + quad * 8;          // mean rows 0..15
        const u16* wp1 = WhT + (size_t)(16 + l16) * 256 + quad * 8;   // logstd rows 16..31
        #pragma unroll
        for (int kt = 0; kt < 8; ++kt) {
            const int k0 = kt * 32;
            const bf16x8 af  = *(const bf16x8*)(ybf + SY(wave * 16 + l16, k0 + quad * 8));
            const bf16x8 bw0 = *(const bf16x8*)(wp0 + k0);
            const bf16x8 bw1 = *(const bf16x8*)(wp1 + k0);
            a0 = __builtin_amdgcn_mfma_f32_16x16x32_bf16(af, bw0, a0, 0, 0, 0);
            a1 = __builtin_amdgcn_mfma_f32_16x16x32_bf16(af, bw1, a1, 0, 0, 0);
        }
        if (l16 < 12) {
            const float bbm = bm[l16], bbs = bs[l16];
            #pragma unroll
            for (int r = 0; r < 4; ++r) {
                const int row = wave * 16 + quad * 4 + r;
                out[(size_t)(row0 + row) * 14 + l16] = a0[r] + bbm;
                lsf[row * 16 + l16] = fminf(fmaxf(a1[r] + bbs, -5.0f), 2.0f);
            }
        }
    }
    __syncthreads();
    if (tid < 64) {
        float s = 0.0f;
        #pragma unroll
        for (int q = 0; q < 12; ++q) s += lsf[tid * 16 + q];
        const float LOG2PI = 1.8378770664093453f;
        out[(size_t)(row0 + tid) * 14 + 12] = -s - 6.0f * LOG2PI;
        out[(size_t)(row0 + tid) * 14 + 13] =  s + 6.0f + 6.0f * LOG2PI;
    }
}

// ---------------------------------------------------------------------------
extern "C" void kernel_launch(void* const* d_in, const int* in_sizes, int n_in,
                              void* d_out, int out_size, void* d_ws, size_t ws_size,
                              hipStream_t stream) {
    (void)in_sizes; (void)n_in; (void)out_size; (void)ws_size;
    const float* x    = (const float*)d_in[0];
    const int*   done = (const int*)  d_in[1];
    const float* h0   = (const float*)d_in[2];
    const float* c0   = (const float*)d_in[3];
    const float* W_ih = (const float*)d_in[4];
    const float* W_hh = (const float*)d_in[5];
    const float* b_ih = (const float*)d_in[6];
    const float* b_hh = (const float*)d_in[7];
    const float* lng  = (const float*)d_in[8];
    const float* lnb  = (const float*)d_in[9];
    const float* W1   = (const float*)d_in[10];
    const float* b1   = (const float*)d_in[11];
    const float* W2   = (const float*)d_in[12];
    const float* b2   = (const float*)d_in[13];
    const float* Wm   = (const float*)d_in[14];
    const float* bm   = (const float*)d_in[15];
    const float* Ws   = (const float*)d_in[16];
    const float* bs   = (const float*)d_in[17];
    float* out = (float*)d_out;

    // workspace carve (~86 MB; ws_size >= 135 MB confirmed)
    unsigned char* p = (unsigned char*)d_ws;
    u16* hs    = (u16*)p;              p += (size_t)(T_ + 1) * BH_ * 2;
    u16* xpad  = (u16*)p;              p += (size_t)T_ * B_ * 64 * 2;
    u16* Wcat  = (u16*)p;              p += (size_t)1024 * KP_ * 2;
    u16* W1T   = (u16*)p;              p += (size_t)M1_ * H_ * 2;
    u16* W2T   = (u16*)p;              p += (size_t)M2_ * M1_ * 2;
    u16* WhT   = (u16*)p;              p += (size_t)32 * H_ * 2;

    prep_xpad<<<(T_ * B_ * 8) / 256, 256, 0, stream>>>(x, xpad);
    prep_weights<<<1824, 256, 0, stream>>>(W_ih, W_hh, W1, W2, Wm, Ws,
                                           Wcat, W1T, W2T, WhT);

    lstm_persist<<<NBLK_, 512, 0, stream>>>(
        xpad, done, h0, c0, hs, Wcat, b_ih, b_hh);

    mlp_mfma64<<<(T_ * B_) / 64, 512, 0, stream>>>(
        hs + BH_, out, lng, lnb, W1T, b1, W2T, b2, WhT, bm, bs);
}

// Round 2
// 1186.561 us; speedup vs baseline: 1.0733x; 1.0733x over previous
//
#include <hip/hip_runtime.h>
#include <hip/hip_bf16.h>
#include <math.h>

#define T_   64
#define B_   2048
#define OBS_ 48
#define H_   256
#define M1_  512
#define M2_  256
#define A_   12
#define BH_  (B_ * H_)
#define KP_  320   // padded K for scan: 64 (x, padded from 48) + 256 (h)
#define GROUPS_  32   // row groups (64 rows each)
#define SLICES_  8    // column-slice blocks per group (32 h-cols each)

typedef unsigned short u16;
typedef __attribute__((ext_vector_type(8))) short bf16x8;
typedef __attribute__((ext_vector_type(4))) float f32x4;

static __device__ __forceinline__ u16 f2b(float f) {
    __hip_bfloat16 h = __float2bfloat16(f);
    return *reinterpret_cast<u16*>(&h);
}
static __device__ __forceinline__ float b2f(u16 u) {
    union { unsigned u32v; float f; } v; v.u32v = ((unsigned)u) << 16; return v.f;
}
static __device__ __forceinline__ float sigm(float x) {
    return 1.0f / (1.0f + __expf(-x));
}
static __device__ __forceinline__ float tanh_fast(float x) {
    x = fminf(fmaxf(x, -15.0f), 15.0f);
    float e = __expf(2.0f * x);
    return (e - 1.0f) / (e + 1.0f);
}
static __device__ __forceinline__ float elu(float x) {
    return x > 0.0f ? x : (__expf(x) - 1.0f);
}

// ---------------------------------------------------------------------------
// Pre-pass kernels
// ---------------------------------------------------------------------------
__global__ void prep_xpad(const float* __restrict__ x, u16* __restrict__ xpad,
                          unsigned* __restrict__ cnt) {
    if (blockIdx.x == 0 && threadIdx.x < GROUPS_) cnt[threadIdx.x] = 0;
    const int gid = blockIdx.x * 256 + threadIdx.x;   // T*B*8 threads
    const int r = gid >> 3, k0 = (gid & 7) * 8;
    u16 tmp[8];
    if (k0 < OBS_) {
        const float4 f0 = *(const float4*)(x + (size_t)r * OBS_ + k0);
        const float4 f1 = *(const float4*)(x + (size_t)r * OBS_ + k0 + 4);
        tmp[0] = f2b(f0.x); tmp[1] = f2b(f0.y); tmp[2] = f2b(f0.z); tmp[3] = f2b(f0.w);
        tmp[4] = f2b(f1.x); tmp[5] = f2b(f1.y); tmp[6] = f2b(f1.z); tmp[7] = f2b(f1.w);
    } else {
        #pragma unroll
        for (int i = 0; i < 8; ++i) tmp[i] = 0;
    }
    *(uint4*)(xpad + (size_t)gid * 8) = *(uint4*)tmp;
}

// Wcat permuted for lstm_sync: out-row = s*128 + (g*2+jh)*16 + jj
//   <- src gate-row g*256 + (s*32 + jh*16 + jj).
// Slice s holds the 128 gate-cols for h-cols [s*32, s*32+32); within a slice,
// frag f = g*2+jh so a wave (fixed jh) holding frags {g*2+jh} gets all 4
// gates of the same j in 4 separate accumulators -> lane-local gate fusion.
__global__ void prep_weights(const float* __restrict__ W_ih, const float* __restrict__ W_hh,
                             const float* __restrict__ W1,  const float* __restrict__ W2,
                             const float* __restrict__ Wm,  const float* __restrict__ Ws,
                             u16* __restrict__ Wcat, u16* __restrict__ W1T,
                             u16* __restrict__ W2T,  u16* __restrict__ WhT) {
    const int b = blockIdx.x, tid = threadIdx.x;
    if (b < 1024) {
        const int s = b >> 7, f = (b >> 4) & 7, jj = b & 15;
        const int g = f >> 1, jh = f & 1;
        const int src = g * 256 + s * 32 + jh * 16 + jj;
        for (int k = tid; k < KP_; k += 256) {
            float v;
            if (k < OBS_)    v = W_ih[src * OBS_ + k];
            else if (k < 64) v = 0.0f;
            else             v = W_hh[src * H_ + (k - 64)];
            Wcat[b * KP_ + k] = f2b(v);
        }
    } else if (b < 1536) {
        const int n = b - 1024;                       // W1T [512][256]
        W1T[n * 256 + tid] = f2b(W1[tid * M1_ + n]);
    } else if (b < 1792) {
        const int n = b - 1536;                       // W2T [256][512]
        W2T[n * 512 + tid]       = f2b(W2[tid * M2_ + n]);
        W2T[n * 512 + tid + 256] = f2b(W2[(tid + 256) * M2_ + n]);
    } else {
        const int n = b - 1792;                       // WhT [32][256]
        float v = 0.0f;
        if (n < 12)                 v = Wm[tid * A_ + n];
        else if (n >= 16 && n < 28) v = Ws[tid * A_ + (n - 16)];
        WhT[n * 256 + tid] = f2b(v);
    }
}

// ---------------------------------------------------------------------------
// Co-resident LSTM scan with N-split + per-group flag sync.
// 256 blocks (32 groups x 8 slices), 512 threads, one block per CU
// (VGPR >128 guarantees 1 block/CU -> all 256 co-resident -> spin is safe).
// Each block: 64 batch rows x 32 h-cols (=128 gate-cols). Its 80 KB weight
// slice lives ENTIRELY in VGPRs (160/lane) for all 64 steps -> zero weight
// memory traffic in the loop. Per step the 8 blocks of a group exchange h
// through hs[t+1] (needed for the MLP anyway): writers use agent-scope (sc1)
// stores so data reaches L3/IF; a per-group monotonic counter gates readers;
// readers then use plain vectorized loads (each hs[t] line is first-touch
// after the flag within this launch; kernel-boundary implicit acquire covers
// cross-iteration staleness). Relaxed atomics only - no wbl2/inv storms.
// ---------------------------------------------------------------------------
#define ASM_(row, chunk) (a_sm + (size_t)(row) * 320 + (size_t)(((chunk) ^ ((row) & 7)) << 3))

__global__ __launch_bounds__(512, 2) void lstm_sync(
    const u16*  __restrict__ xpad,   // [T][B][64] bf16
    const int*  __restrict__ done,   // [T][B]
    const float* __restrict__ h0,    // [B][256] fp32
    const float* __restrict__ c0,    // [B][256] fp32
    u16*        __restrict__ hs,     // [T+1][B][256] bf16; slices 1..T written
    const u16*  __restrict__ Wcat,   // [1024 permuted][320] bf16
    const float* __restrict__ b_ih,
    const float* __restrict__ b_hh,
    unsigned*   __restrict__ cnt)    // [GROUPS_] arrival counters (zeroed by prep)
{
    __shared__ u16 a_sm[64 * 320];   // 40 KB, XOR-swizzled

    const int tid  = threadIdx.x;
    const int lane = tid & 63;
    const int wave = tid >> 6;               // 0..7
    const int quad = lane >> 4, l16 = lane & 15;
    const int rowq = wave >> 1;              // 0..3: rows rowq*16 .. +16
    const int jh   = wave & 1;               // j-half within slice
    const int grp  = blockIdx.x >> 3;        // 0..31
    const int s    = blockIdx.x & 7;         // 0..7
    const int b0   = grp * 64;
    const int j    = s * 32 + jh * 16 + l16; // this lane's h column (0..255)

    // ---- fused biases: 4 gates of column j ----
    float bsum[4];
    #pragma unroll
    for (int g = 0; g < 4; ++g) bsum[g] = b_ih[g * 256 + j] + b_hh[g * 256 + j];

    // ---- persistent c state (pre-masked with done[0]) ----
    float cst[4];
    #pragma unroll
    for (int r = 0; r < 4; ++r) {
        const int row = b0 + rowq * 16 + quad * 4 + r;
        cst[r] = done[row] ? 0.0f : c0[(size_t)row * H_ + j];
    }

    // ---- the ENTIRE weight slice, register-resident: 4 gates x 10 kt ----
    bf16x8 Bs[4][10];
    #pragma unroll
    for (int g = 0; g < 4; ++g) {
        const u16* wp = Wcat + (size_t)(s * 128 + (g * 2 + jh) * 16 + l16) * KP_ + quad * 8;
        #pragma unroll
        for (int kt = 0; kt < 10; ++kt)
            Bs[g][kt] = *(const bf16x8*)(wp + kt * 32);
    }

    const int srow = tid >> 3, sseg = tid & 7;   // staging map: 64 rows x 8 segs

    for (int t = 0; t < T_; ++t) {
        // ---- wait for the group's h(t) (t>=1) ----
        if (t > 0 && tid == 0) {
            const unsigned target = (unsigned)(SLICES_ * t);
            int guard = 0;
            while (__hip_atomic_load(&cnt[grp], __ATOMIC_RELAXED,
                                     __HIP_MEMORY_SCOPE_AGENT) < target) {
                __builtin_amdgcn_s_sleep(1);
                if (++guard > (1 << 24)) break;   // deadlock -> wrong answer, not hang
            }
        }
        __syncthreads();

        // ---- stage x(t) ----
        *(uint4*)ASM_(srow, sseg) =
            *(const uint4*)(xpad + ((size_t)t * B_ + b0 + srow) * 64 + sseg * 8);

        // ---- stage h(t), masked by done[t] ----
        const int dn = done[(size_t)t * B_ + b0 + srow];
        if (t == 0) {
            const float* hrow = h0 + (size_t)(b0 + srow) * H_;
            #pragma unroll
            for (int i = 0; i < 4; ++i) {
                const int col = sseg * 32 + i * 8;
                u16 tmp[8];
                #pragma unroll
                for (int e = 0; e < 8; ++e) tmp[e] = dn ? (u16)0 : f2b(hrow[col + e]);
                *(uint4*)ASM_(srow, 8 + sseg * 4 + i) = *(uint4*)tmp;
            }
        } else {
            const u16* hrow = hs + (size_t)t * BH_ + (size_t)(b0 + srow) * H_;
            #pragma unroll
            for (int i = 0; i < 4; ++i) {
                uint4 hv = *(const uint4*)(hrow + sseg * 32 + i * 8);
                if (dn) hv = make_uint4(0u, 0u, 0u, 0u);
                *(uint4*)ASM_(srow, 8 + sseg * 4 + i) = hv;
            }
        }
        __syncthreads();

        // ---- GEMM: 10 ds_read + 40 MFMA per wave; B entirely from VGPRs ----
        f32x4 acc[4];
        #pragma unroll
        for (int g = 0; g < 4; ++g) acc[g] = (f32x4){0, 0, 0, 0};
        #pragma unroll
        for (int kt = 0; kt < 10; ++kt) {
            const bf16x8 af = *(const bf16x8*)ASM_(rowq * 16 + l16, kt * 4 + quad);
            #pragma unroll
            for (int g = 0; g < 4; ++g)
                acc[g] = __builtin_amdgcn_mfma_f32_16x16x32_bf16(af, Bs[g][kt], acc[g], 0, 0, 0);
        }

        // ---- epilogue: lane-local gate fusion; h -> hs[t+1] via sc1 stores ----
        u16* hs1 = hs + (size_t)(t + 1) * BH_;
        #pragma unroll
        for (int r = 0; r < 4; ++r) {
            const int rowg = b0 + rowq * 16 + quad * 4 + r;
            const float gi = acc[0][r] + bsum[0];
            const float gf = acc[1][r] + bsum[1];
            const float gg = acc[2][r] + bsum[2];
            const float go = acc[3][r] + bsum[3];
            const float cn = sigm(gf) * cst[r] + sigm(gi) * tanh_fast(gg);
            const float h  = sigm(go) * tanh_fast(cn);
            const float kp = (t + 1 < T_)
                ? (done[(size_t)(t + 1) * B_ + rowg] ? 0.0f : 1.0f) : 1.0f;
            cst[r] = cn * kp;                      // pre-mask c for step t+1
            const unsigned hb = (unsigned)f2b(h);
            const unsigned ob = (unsigned)__shfl_xor((int)hb, 1);
            if ((l16 & 1) == 0) {                  // pack (j, j+1) -> one u32 store
                const unsigned val = hb | (ob << 16);
                __hip_atomic_store((unsigned*)(hs1 + (size_t)rowg * H_ + (j & ~1)), val,
                                   __ATOMIC_RELAXED, __HIP_MEMORY_SCOPE_AGENT);
            }
        }
        __syncthreads();   // drains vmcnt (sc1 stores at L3) before the flag
        if (tid == 0 && t + 1 < T_)
            __hip_atomic_fetch_add(&cnt[grp], 1u, __ATOMIC_RELAXED,
                                   __HIP_MEMORY_SCOPE_AGENT);
    }
}

// ---------------------------------------------------------------------------
// MLP v2 (unchanged, proven): 64 rows/block, 512 threads, two-phase y1.
// ---------------------------------------------------------------------------
#define SY(row, col) ((size_t)(row) * 256 + ((((col) >> 3) ^ ((row) & 7)) << 3) + ((col) & 7))

__global__ __launch_bounds__(512, 4) void mlp_mfma64(
    const u16*  __restrict__ hs,    // [nrows][256] bf16
    float*      __restrict__ out,   // [nrows][14]
    const float* __restrict__ lng, const float* __restrict__ lnb,
    const u16*  __restrict__ W1T, const float* __restrict__ b1,
    const u16*  __restrict__ W2T, const float* __restrict__ b2,
    const u16*  __restrict__ WhT,
    const float* __restrict__ bm, const float* __restrict__ bs)
{
    __shared__ u16 ybf[64 * 256];   // 32 KB swizzled: LN output, later y2
    __shared__ u16 yh [64 * 256];   // 32 KB swizzled: y1 column-half; later ls overlay

    const int tid  = threadIdx.x;
    const int lane = tid & 63;
    const int wave = tid >> 6;        // 0..7
    const int quad = lane >> 4, l16 = lane & 15;
    const int row0 = blockIdx.x * 64;

    // ---- LayerNorm: wave w -> rows w*8..w*8+7; lane holds 4 cols ----
    {
        const float4 gv = *(const float4*)(lng + lane * 4);
        const float4 bv = *(const float4*)(lnb + lane * 4);
        #pragma unroll
        for (int rr = 0; rr < 8; ++rr) {
            const int r = wave * 8 + rr;
            const ushort4 hv = *(const ushort4*)(hs + (size_t)(row0 + r) * H_ + lane * 4);
            const float v0 = b2f(hv.x), v1 = b2f(hv.y), v2 = b2f(hv.z), v3 = b2f(hv.w);
            float s  = v0 + v1 + v2 + v3;
            float ss = v0 * v0 + v1 * v1 + v2 * v2 + v3 * v3;
            #pragma unroll
            for (int off = 32; off > 0; off >>= 1) {
                s  += __shfl_down(s,  off);
                ss += __shfl_down(ss, off);
            }
            s = __shfl(s, 0); ss = __shfl(ss, 0);
            const float mu   = s * (1.0f / 256.0f);
            const float rstd = rsqrtf(ss * (1.0f / 256.0f) - mu * mu + 1e-5f);
            ushort4 o;
            o.x = f2b((v0 - mu) * rstd * gv.x + bv.x);
            o.y = f2b((v1 - mu) * rstd * gv.y + bv.y);
            o.z = f2b((v2 - mu) * rstd * gv.z + bv.z);
            o.w = f2b((v3 - mu) * rstd * gv.w + bv.w);
            *(ushort4*)(ybf + SY(r, lane * 4)) = o;
        }
    }
    __syncthreads();

    // ---- L2 partial accumulators: live across both phases ----
    f32x4 acc2[4][2];
    #pragma unroll
    for (int m = 0; m < 4; ++m)
        #pragma unroll
        for (int j = 0; j < 2; ++j) acc2[m][j] = (f32x4){0,0,0,0};

    #pragma unroll
    for (int ph = 0; ph < 2; ++ph) {
        // ---- L1 phase: y1 cols [ph*256, ph*256+256); wave n-slice 32 cols ----
        {
            f32x4 acc[4][2];
            #pragma unroll
            for (int m = 0; m < 4; ++m)
                #pragma unroll
                for (int j = 0; j < 2; ++j) acc[m][j] = (f32x4){0,0,0,0};
            const int n0 = ph * 256 + wave * 32;
            const u16* wp0 = W1T + (size_t)(n0 + l16) * 256 + quad * 8;
            const u16* wp1 = W1T + (size_t)(n0 + 16 + l16) * 256 + quad * 8;
            #pragma unroll
            for (int kt = 0; kt < 8; ++kt) {
                const int k0 = kt * 32;
                const bf16x8 bw0 = *(const bf16x8*)(wp0 + k0);
                const bf16x8 bw1 = *(const bf16x8*)(wp1 + k0);
                #pragma unroll
                for (int m = 0; m < 4; ++m) {
                    const bf16x8 af = *(const bf16x8*)(ybf + SY(m * 16 + l16, k0 + quad * 8));
                    acc[m][0] = __builtin_amdgcn_mfma_f32_16x16x32_bf16(af, bw0, acc[m][0], 0, 0, 0);
                    acc[m][1] = __builtin_amdgcn_mfma_f32_16x16x32_bf16(af, bw1, acc[m][1], 0, 0, 0);
                }
            }
            const float bb0 = b1[n0 + l16], bb1 = b1[n0 + 16 + l16];
            __syncthreads();   // yh free (prev phase consumed / first use)
            #pragma unroll
            for (int m = 0; m < 4; ++m)
                #pragma unroll
                for (int r = 0; r < 4; ++r) {
                    const int row = m * 16 + quad * 4 + r;
                    yh[SY(row, wave * 32 + l16)]      = f2b(elu(acc[m][0][r] + bb0));
                    yh[SY(row, wave * 32 + 16 + l16)] = f2b(elu(acc[m][1][r] + bb1));
                }
        }
        __syncthreads();

        // ---- L2 partial: K in [ph*256, ph*256+256); wave n-slice 32 cols ----
        {
            const int n0 = wave * 32;
            const u16* wp0 = W2T + (size_t)(n0 + l16) * 512 + ph * 256 + quad * 8;
            const u16* wp1 = W2T + (size_t)(n0 + 16 + l16) * 512 + ph * 256 + quad * 8;
            #pragma unroll
            for (int kt = 0; kt < 8; ++kt) {
                const int k0 = kt * 32;
                const bf16x8 bw0 = *(const bf16x8*)(wp0 + k0);
                const bf16x8 bw1 = *(const bf16x8*)(wp1 + k0);
                #pragma unroll
                for (int m = 0; m < 4; ++m) {
                    const bf16x8 af = *(const bf16x8*)(yh + SY(m * 16 + l16, k0 + quad * 8));
                    acc2[m][0] = __builtin_amdgcn_mfma_f32_16x16x32_bf16(af, bw0, acc2[m][0], 0, 0, 0);
                    acc2[m][1] = __builtin_amdgcn_mfma_f32_16x16x32_bf16(af, bw1, acc2[m][1], 0, 0, 0);
                }
            }
        }
        __syncthreads();
    }

    // ---- y2 = elu(acc2 + b2) -> ybf (LN data fully consumed) ----
    {
        const float bb0 = b2[wave * 32 + l16], bb1 = b2[wave * 32 + 16 + l16];
        #pragma unroll
        for (int m = 0; m < 4; ++m)
            #pragma unroll
            for (int r = 0; r < 4; ++r) {
                const int row = m * 16 + quad * 4 + r;
                ybf[SY(row, wave * 32 + l16)]      = f2b(elu(acc2[m][0][r] + bb0));
                ybf[SY(row, wave * 32 + 16 + l16)] = f2b(elu(acc2[m][1][r] + bb1));
            }
    }
    __syncthreads();

    // ---- Heads: waves 0..3 -> m-frag = wave; j=0 mean, j=1 logstd ----
    float* lsf = (float*)yh;   // overlay: [64][16] floats (yh free)
    if (wave < 4) {
        f32x4 a0 = {0,0,0,0}, a1 = {0,0,0,0};
        const u16* wp0 = WhT + (size_t)l16 * 256 + quad * 8;          // mean rows 0..15
        const u16* wp1 = WhT + (size_t)(16 + l16) * 256 + quad * 8;   // logstd rows 16..31
        #pragma unroll
        for (int kt = 0; kt < 8; ++kt) {
            const int k0 = kt * 32;
            const bf16x8 af  = *(const bf16x8*)(ybf + SY(wave * 16 + l16, k0 + quad * 8));
            const bf16x8 bw0 = *(const bf16x8*)(wp0 + k0);
            const bf16x8 bw1 = *(const bf16x8*)(wp1 + k0);
            a0 = __builtin_amdgcn_mfma_f32_16x16x32_bf16(af, bw0, a0, 0, 0, 0);
            a1 = __builtin_amdgcn_mfma_f32_16x16x32_bf16(af, bw1, a1, 0, 0, 0);
        }
        if (l16 < 12) {
            const float bbm = bm[l16], bbs = bs[l16];
            #pragma unroll
            for (int r = 0; r < 4; ++r) {
                const int row = wave * 16 + quad * 4 + r;
                out[(size_t)(row0 + row) * 14 + l16] = a0[r] + bbm;
                lsf[row * 16 + l16] = fminf(fmaxf(a1[r] + bbs, -5.0f), 2.0f);
            }
        }
    }
    __syncthreads();
    if (tid < 64) {
        float s = 0.0f;
        #pragma unroll
        for (int q = 0; q < 12; ++q) s += lsf[tid * 16 + q];
        const float LOG2PI = 1.8378770664093453f;
        out[(size_t)(row0 + tid) * 14 + 12] = -s - 6.0f * LOG2PI;
        out[(size_t)(row0 + tid) * 14 + 13] =  s + 6.0f + 6.0f * LOG2PI;
    }
}

// ---------------------------------------------------------------------------
extern "C" void kernel_launch(void* const* d_in, const int* in_sizes, int n_in,
                              void* d_out, int out_size, void* d_ws, size_t ws_size,
                              hipStream_t stream) {
    (void)in_sizes; (void)n_in; (void)out_size; (void)ws_size;
    const float* x    = (const float*)d_in[0];
    const int*   done = (const int*)  d_in[1];
    const float* h0   = (const float*)d_in[2];
    const float* c0   = (const float*)d_in[3];
    const float* W_ih = (const float*)d_in[4];
    const float* W_hh = (const float*)d_in[5];
    const float* b_ih = (const float*)d_in[6];
    const float* b_hh = (const float*)d_in[7];
    const float* lng  = (const float*)d_in[8];
    const float* lnb  = (const float*)d_in[9];
    const float* W1   = (const float*)d_in[10];
    const float* b1   = (const float*)d_in[11];
    const float* W2   = (const float*)d_in[12];
    const float* b2   = (const float*)d_in[13];
    const float* Wm   = (const float*)d_in[14];
    const float* bm   = (const float*)d_in[15];
    const float* Ws   = (const float*)d_in[16];
    const float* bs   = (const float*)d_in[17];
    float* out = (float*)d_out;

    // workspace carve (~52 MB; ws_size >= 135 MB confirmed)
    unsigned char* p = (unsigned char*)d_ws;
    u16* hs    = (u16*)p;              p += (size_t)(T_ + 1) * BH_ * 2;
    u16* xpad  = (u16*)p;              p += (size_t)T_ * B_ * 64 * 2;
    u16* Wcat  = (u16*)p;              p += (size_t)1024 * KP_ * 2;
    u16* W1T   = (u16*)p;              p += (size_t)M1_ * H_ * 2;
    u16* W2T   = (u16*)p;              p += (size_t)M2_ * M1_ * 2;
    u16* WhT   = (u16*)p;              p += (size_t)32 * H_ * 2;
    unsigned* cnt = (unsigned*)p;      p += 128;

    prep_xpad<<<(T_ * B_ * 8) / 256, 256, 0, stream>>>(x, xpad, cnt);
    prep_weights<<<1824, 256, 0, stream>>>(W_ih, W_hh, W1, W2, Wm, Ws,
                                           Wcat, W1T, W2T, WhT);

    lstm_sync<<<GROUPS_ * SLICES_, 512, 0, stream>>>(
        xpad, done, h0, c0, hs, Wcat, b_ih, b_hh, cnt);

    mlp_mfma64<<<(T_ * B_) / 64, 512, 0, stream>>>(
        hs + BH_, out, lng, lnb, W1T, b1, W2T, b2, WhT, bm, bs);
}

// Round 3
// 878.034 us; speedup vs baseline: 1.4504x; 1.3514x over previous
//
#include <hip/hip_runtime.h>
#include <hip/hip_bf16.h>
#include <math.h>

#define T_   64
#define B_   2048
#define OBS_ 48
#define H_   256
#define M1_  512
#define M2_  256
#define A_   12
#define BH_  (B_ * H_)
#define KP_  320   // padded K for scan: 64 (x, padded from 48) + 256 (h)
#define GROUPS_  64   // row groups (32 rows each)
#define SLICES_  4    // column-slice blocks per group (64 h-cols each)
#define RPB_     32   // rows per block

typedef unsigned short u16;
typedef __attribute__((ext_vector_type(8))) short bf16x8;
typedef __attribute__((ext_vector_type(4))) float f32x4;

static __device__ __forceinline__ u16 f2b(float f) {
    __hip_bfloat16 h = __float2bfloat16(f);
    return *reinterpret_cast<u16*>(&h);
}
static __device__ __forceinline__ float b2f(u16 u) {
    union { unsigned u32v; float f; } v; v.u32v = ((unsigned)u) << 16; return v.f;
}
static __device__ __forceinline__ float sigm(float x) {
    return 1.0f / (1.0f + __expf(-x));
}
static __device__ __forceinline__ float tanh_fast(float x) {
    x = fminf(fmaxf(x, -15.0f), 15.0f);
    float e = __expf(2.0f * x);
    return (e - 1.0f) / (e + 1.0f);
}
static __device__ __forceinline__ float elu(float x) {
    return x > 0.0f ? x : (__expf(x) - 1.0f);
}

// ---------------------------------------------------------------------------
// Pre-pass kernels
// ---------------------------------------------------------------------------
__global__ void prep_xpad(const float* __restrict__ x, u16* __restrict__ xpad,
                          unsigned* __restrict__ cnt) {
    if (blockIdx.x == 0 && threadIdx.x < GROUPS_) cnt[threadIdx.x] = 0;
    const int gid = blockIdx.x * 256 + threadIdx.x;   // T*B*8 threads
    const int r = gid >> 3, k0 = (gid & 7) * 8;
    u16 tmp[8];
    if (k0 < OBS_) {
        const float4 f0 = *(const float4*)(x + (size_t)r * OBS_ + k0);
        const float4 f1 = *(const float4*)(x + (size_t)r * OBS_ + k0 + 4);
        tmp[0] = f2b(f0.x); tmp[1] = f2b(f0.y); tmp[2] = f2b(f0.z); tmp[3] = f2b(f0.w);
        tmp[4] = f2b(f1.x); tmp[5] = f2b(f1.y); tmp[6] = f2b(f1.z); tmp[7] = f2b(f1.w);
    } else {
        #pragma unroll
        for (int i = 0; i < 8; ++i) tmp[i] = 0;
    }
    *(uint4*)(xpad + (size_t)gid * 8) = *(uint4*)tmp;
}

// Wcat permuted for lstm_sync (GROUPS=64/SLICES=4):
//   out-row = ((s*4 + colq)*4 + g)*16 + jj  <-  src gate-row g*256 + (s*64 + colq*16 + jj)
// Slice s owns h-cols [s*64, s*64+64). Wave (rowq,colq) holds the 4 gates of
// h-cols [s*64+colq*16, +16) as 4 separate B-frags -> lane-local gate fusion.
__global__ void prep_weights(const float* __restrict__ W_ih, const float* __restrict__ W_hh,
                             const float* __restrict__ W1,  const float* __restrict__ W2,
                             const float* __restrict__ Wm,  const float* __restrict__ Ws,
                             u16* __restrict__ Wcat, u16* __restrict__ W1T,
                             u16* __restrict__ W2T,  u16* __restrict__ WhT) {
    const int b = blockIdx.x, tid = threadIdx.x;
    if (b < 1024) {
        const int s = b >> 8, colq = (b >> 6) & 3, g = (b >> 4) & 3, jj = b & 15;
        const int src = g * 256 + s * 64 + colq * 16 + jj;
        for (int k = tid; k < KP_; k += 256) {
            float v;
            if (k < OBS_)    v = W_ih[src * OBS_ + k];
            else if (k < 64) v = 0.0f;
            else             v = W_hh[src * H_ + (k - 64)];
            Wcat[b * KP_ + k] = f2b(v);
        }
    } else if (b < 1536) {
        const int n = b - 1024;                       // W1T [512][256]
        W1T[n * 256 + tid] = f2b(W1[tid * M1_ + n]);
    } else if (b < 1792) {
        const int n = b - 1536;                       // W2T [256][512]
        W2T[n * 512 + tid]       = f2b(W2[tid * M2_ + n]);
        W2T[n * 512 + tid + 256] = f2b(W2[(tid + 256) * M2_ + n]);
    } else {
        const int n = b - 1792;                       // WhT [32][256]
        float v = 0.0f;
        if (n < 12)                 v = Wm[tid * A_ + n];
        else if (n >= 16 && n < 28) v = Ws[tid * A_ + (n - 16)];
        WhT[n * 256 + tid] = f2b(v);
    }
}

// ---------------------------------------------------------------------------
// Co-resident LSTM scan, round-3 topology fix:
//  - 256 blocks (64 groups x 4 slices), 512 threads.
//  - ONE block per CU, forced via 64 KB dynamic-LDS request at launch
//    (20 KB static + 64 KB dyn = 84 KB > 160/2 KB). Round-2's 2-blocks/CU
//    packing idled half the chip (Occupancy 24% = 16 waves on 128 CUs).
//  - Each block: 32 rows x 64 h-cols; its 160 KB weight slice is split over
//    8 waves (40 VGPRs/lane), fully register-resident for all 64 steps.
//  - Sync protocol identical to round 2 (proven): sc1 relaxed-atomic h
//    stores -> syncthreads (vmcnt drain) -> per-group counter fetch_add;
//    readers poll the counter then plain-load h (fresh lines -> L3 hit).
//  - x(t) staging overlaps the poll (511 threads stage while tid 0 spins).
// ---------------------------------------------------------------------------
#define ASM_(row, chunk) (a_sm + (size_t)(row) * 320 + (size_t)(((chunk) ^ ((row) & 7)) << 3))

__global__ __launch_bounds__(512, 2) void lstm_sync(
    const u16*  __restrict__ xpad,   // [T][B][64] bf16
    const int*  __restrict__ done,   // [T][B]
    const float* __restrict__ h0,    // [B][256] fp32
    const float* __restrict__ c0,    // [B][256] fp32
    u16*        __restrict__ hs,     // [T+1][B][256] bf16; slices 1..T written
    const u16*  __restrict__ Wcat,   // [1024 permuted][320] bf16
    const float* __restrict__ b_ih,
    const float* __restrict__ b_hh,
    unsigned*   __restrict__ cnt)    // [GROUPS_] arrival counters (zeroed by prep)
{
    __shared__ u16 a_sm[RPB_ * 320];   // 20 KB static (+64 KB dynamic pad at launch)

    const int tid  = threadIdx.x;
    const int lane = tid & 63;
    const int wave = tid >> 6;               // 0..7
    const int quad = lane >> 4, l16 = lane & 15;
    const int rowq = wave >> 2;              // 0..1: rows rowq*16 .. +16
    const int colq = wave & 3;               // 0..3: 16-col group within slice
    const int grp  = blockIdx.x >> 2;        // 0..63
    const int s    = blockIdx.x & 3;         // 0..3
    const int b0   = grp * RPB_;
    const int j    = s * 64 + colq * 16 + l16;   // this lane's h column (0..255)

    // ---- fused biases: 4 gates of column j ----
    float bsum[4];
    #pragma unroll
    for (int g = 0; g < 4; ++g) bsum[g] = b_ih[g * 256 + j] + b_hh[g * 256 + j];

    // ---- persistent c state (pre-masked with done[0]) ----
    float cst[4];
    #pragma unroll
    for (int r = 0; r < 4; ++r) {
        const int row = b0 + rowq * 16 + quad * 4 + r;
        cst[r] = done[row] ? 0.0f : c0[(size_t)row * H_ + j];
    }

    // ---- this wave's weight slice, register-resident: 4 gates x 10 kt ----
    bf16x8 Bs[4][10];
    #pragma unroll
    for (int g = 0; g < 4; ++g) {
        const u16* wp = Wcat + (size_t)(((s * 4 + colq) * 4 + g) * 16 + l16) * KP_ + quad * 8;
        #pragma unroll
        for (int kt = 0; kt < 10; ++kt)
            Bs[g][kt] = *(const bf16x8*)(wp + kt * 32);
    }

    const int srow = tid >> 4, sseg = tid & 15;   // staging map: 32 rows x 16 segs

    for (int t = 0; t < T_; ++t) {
        // ---- stage x(t) (256 threads) while tid 0 polls for h(t) ----
        if (sseg < 8)
            *(uint4*)ASM_(srow, sseg) =
                *(const uint4*)(xpad + ((size_t)t * B_ + b0 + srow) * 64 + sseg * 8);
        if (t > 0 && tid == 0) {
            const unsigned target = (unsigned)(SLICES_ * t);
            int guard = 0;
            while (__hip_atomic_load(&cnt[grp], __ATOMIC_RELAXED,
                                     __HIP_MEMORY_SCOPE_AGENT) < target) {
                __builtin_amdgcn_s_sleep(1);
                if (++guard > (1 << 24)) break;   // deadlock -> wrong answer, not hang
            }
        }
        __syncthreads();

        // ---- stage h(t), masked by done[t]: 2 x uint4 per thread ----
        const int dn = done[(size_t)t * B_ + b0 + srow];
        if (t == 0) {
            const float* hrow = h0 + (size_t)(b0 + srow) * H_;
            #pragma unroll
            for (int i = 0; i < 2; ++i) {
                const int col = sseg * 16 + i * 8;
                u16 tmp[8];
                #pragma unroll
                for (int e = 0; e < 8; ++e) tmp[e] = dn ? (u16)0 : f2b(hrow[col + e]);
                *(uint4*)ASM_(srow, 8 + sseg * 2 + i) = *(uint4*)tmp;
            }
        } else {
            const u16* hrow = hs + (size_t)t * BH_ + (size_t)(b0 + srow) * H_;
            #pragma unroll
            for (int i = 0; i < 2; ++i) {
                uint4 hv = *(const uint4*)(hrow + sseg * 16 + i * 8);
                if (dn) hv = make_uint4(0u, 0u, 0u, 0u);
                *(uint4*)ASM_(srow, 8 + sseg * 2 + i) = hv;
            }
        }
        __syncthreads();

        // ---- GEMM: 10 ds_read + 40 MFMA per wave; B entirely from VGPRs ----
        f32x4 acc[4];
        #pragma unroll
        for (int g = 0; g < 4; ++g) acc[g] = (f32x4){0, 0, 0, 0};
        #pragma unroll
        for (int kt = 0; kt < 10; ++kt) {
            const bf16x8 af = *(const bf16x8*)ASM_(rowq * 16 + l16, kt * 4 + quad);
            #pragma unroll
            for (int g = 0; g < 4; ++g)
                acc[g] = __builtin_amdgcn_mfma_f32_16x16x32_bf16(af, Bs[g][kt], acc[g], 0, 0, 0);
        }

        // ---- epilogue: lane-local gate fusion; h -> hs[t+1] via sc1 stores ----
        u16* hs1 = hs + (size_t)(t + 1) * BH_;
        #pragma unroll
        for (int r = 0; r < 4; ++r) {
            const int rowg = b0 + rowq * 16 + quad * 4 + r;
            const float gi = acc[0][r] + bsum[0];
            const float gf = acc[1][r] + bsum[1];
            const float gg = acc[2][r] + bsum[2];
            const float go = acc[3][r] + bsum[3];
            const float cn = sigm(gf) * cst[r] + sigm(gi) * tanh_fast(gg);
            const float h  = sigm(go) * tanh_fast(cn);
            const float kp = (t + 1 < T_)
                ? (done[(size_t)(t + 1) * B_ + rowg] ? 0.0f : 1.0f) : 1.0f;
            cst[r] = cn * kp;                      // pre-mask c for step t+1
            const unsigned hb = (unsigned)f2b(h);
            const unsigned ob = (unsigned)__shfl_xor((int)hb, 1);
            if ((l16 & 1) == 0) {                  // pack (j, j+1) -> one u32 store
                const unsigned val = hb | (ob << 16);
                __hip_atomic_store((unsigned*)(hs1 + (size_t)rowg * H_ + (j & ~1)), val,
                                   __ATOMIC_RELAXED, __HIP_MEMORY_SCOPE_AGENT);
            }
        }
        __syncthreads();   // drains vmcnt (sc1 stores at L3) before the flag
        if (tid == 0 && t + 1 < T_)
            __hip_atomic_fetch_add(&cnt[grp], 1u, __ATOMIC_RELAXED,
                                   __HIP_MEMORY_SCOPE_AGENT);
    }
}

// ---------------------------------------------------------------------------
// MLP v2 (unchanged, proven): 64 rows/block, 512 threads, two-phase y1.
// ---------------------------------------------------------------------------
#define SY(row, col) ((size_t)(row) * 256 + ((((col) >> 3) ^ ((row) & 7)) << 3) + ((col) & 7))

__global__ __launch_bounds__(512, 4) void mlp_mfma64(
    const u16*  __restrict__ hs,    // [nrows][256] bf16
    float*      __restrict__ out,   // [nrows][14]
    const float* __restrict__ lng, const float* __restrict__ lnb,
    const u16*  __restrict__ W1T, const float* __restrict__ b1,
    const u16*  __restrict__ W2T, const float* __restrict__ b2,
    const u16*  __restrict__ WhT,
    const float* __restrict__ bm, const float* __restrict__ bs)
{
    __shared__ u16 ybf[64 * 256];   // 32 KB swizzled: LN output, later y2
    __shared__ u16 yh [64 * 256];   // 32 KB swizzled: y1 column-half; later ls overlay

    const int tid  = threadIdx.x;
    const int lane = tid & 63;
    const int wave = tid >> 6;        // 0..7
    const int quad = lane >> 4, l16 = lane & 15;
    const int row0 = blockIdx.x * 64;

    // ---- LayerNorm: wave w -> rows w*8..w*8+7; lane holds 4 cols ----
    {
        const float4 gv = *(const float4*)(lng + lane * 4);
        const float4 bv = *(const float4*)(lnb + lane * 4);
        #pragma unroll
        for (int rr = 0; rr < 8; ++rr) {
            const int r = wave * 8 + rr;
            const ushort4 hv = *(const ushort4*)(hs + (size_t)(row0 + r) * H_ + lane * 4);
            const float v0 = b2f(hv.x), v1 = b2f(hv.y), v2 = b2f(hv.z), v3 = b2f(hv.w);
            float s  = v0 + v1 + v2 + v3;
            float ss = v0 * v0 + v1 * v1 + v2 * v2 + v3 * v3;
            #pragma unroll
            for (int off = 32; off > 0; off >>= 1) {
                s  += __shfl_down(s,  off);
                ss += __shfl_down(ss, off);
            }
            s = __shfl(s, 0); ss = __shfl(ss, 0);
            const float mu   = s * (1.0f / 256.0f);
            const float rstd = rsqrtf(ss * (1.0f / 256.0f) - mu * mu + 1e-5f);
            ushort4 o;
            o.x = f2b((v0 - mu) * rstd * gv.x + bv.x);
            o.y = f2b((v1 - mu) * rstd * gv.y + bv.y);
            o.z = f2b((v2 - mu) * rstd * gv.z + bv.z);
            o.w = f2b((v3 - mu) * rstd * gv.w + bv.w);
            *(ushort4*)(ybf + SY(r, lane * 4)) = o;
        }
    }
    __syncthreads();

    // ---- L2 partial accumulators: live across both phases ----
    f32x4 acc2[4][2];
    #pragma unroll
    for (int m = 0; m < 4; ++m)
        #pragma unroll
        for (int j = 0; j < 2; ++j) acc2[m][j] = (f32x4){0,0,0,0};

    #pragma unroll
    for (int ph = 0; ph < 2; ++ph) {
        // ---- L1 phase: y1 cols [ph*256, ph*256+256); wave n-slice 32 cols ----
        {
            f32x4 acc[4][2];
            #pragma unroll
            for (int m = 0; m < 4; ++m)
                #pragma unroll
                for (int j = 0; j < 2; ++j) acc[m][j] = (f32x4){0,0,0,0};
            const int n0 = ph * 256 + wave * 32;
            const u16* wp0 = W1T + (size_t)(n0 + l16) * 256 + quad * 8;
            const u16* wp1 = W1T + (size_t)(n0 + 16 + l16) * 256 + quad * 8;
            #pragma unroll
            for (int kt = 0; kt < 8; ++kt) {
                const int k0 = kt * 32;
                const bf16x8 bw0 = *(const bf16x8*)(wp0 + k0);
                const bf16x8 bw1 = *(const bf16x8*)(wp1 + k0);
                #pragma unroll
                for (int m = 0; m < 4; ++m) {
                    const bf16x8 af = *(const bf16x8*)(ybf + SY(m * 16 + l16, k0 + quad * 8));
                    acc[m][0] = __builtin_amdgcn_mfma_f32_16x16x32_bf16(af, bw0, acc[m][0], 0, 0, 0);
                    acc[m][1] = __builtin_amdgcn_mfma_f32_16x16x32_bf16(af, bw1, acc[m][1], 0, 0, 0);
                }
            }
            const float bb0 = b1[n0 + l16], bb1 = b1[n0 + 16 + l16];
            __syncthreads();   // yh free (prev phase consumed / first use)
            #pragma unroll
            for (int m = 0; m < 4; ++m)
                #pragma unroll
                for (int r = 0; r < 4; ++r) {
                    const int row = m * 16 + quad * 4 + r;
                    yh[SY(row, wave * 32 + l16)]      = f2b(elu(acc[m][0][r] + bb0));
                    yh[SY(row, wave * 32 + 16 + l16)] = f2b(elu(acc[m][1][r] + bb1));
                }
        }
        __syncthreads();

        // ---- L2 partial: K in [ph*256, ph*256+256); wave n-slice 32 cols ----
        {
            const int n0 = wave * 32;
            const u16* wp0 = W2T + (size_t)(n0 + l16) * 512 + ph * 256 + quad * 8;
            const u16* wp1 = W2T + (size_t)(n0 + 16 + l16) * 512 + ph * 256 + quad * 8;
            #pragma unroll
            for (int kt = 0; kt < 8; ++kt) {
                const int k0 = kt * 32;
                const bf16x8 bw0 = *(const bf16x8*)(wp0 + k0);
                const bf16x8 bw1 = *(const bf16x8*)(wp1 + k0);
                #pragma unroll
                for (int m = 0; m < 4; ++m) {
                    const bf16x8 af = *(const bf16x8*)(yh + SY(m * 16 + l16, k0 + quad * 8));
                    acc2[m][0] = __builtin_amdgcn_mfma_f32_16x16x32_bf16(af, bw0, acc2[m][0], 0, 0, 0);
                    acc2[m][1] = __builtin_amdgcn_mfma_f32_16x16x32_bf16(af, bw1, acc2[m][1], 0, 0, 0);
                }
            }
        }
        __syncthreads();
    }

    // ---- y2 = elu(acc2 + b2) -> ybf (LN data fully consumed) ----
    {
        const float bb0 = b2[wave * 32 + l16], bb1 = b2[wave * 32 + 16 + l16];
        #pragma unroll
        for (int m = 0; m < 4; ++m)
            #pragma unroll
            for (int r = 0; r < 4; ++r) {
                const int row = m * 16 + quad * 4 + r;
                ybf[SY(row, wave * 32 + l16)]      = f2b(elu(acc2[m][0][r] + bb0));
                ybf[SY(row, wave * 32 + 16 + l16)] = f2b(elu(acc2[m][1][r] + bb1));
            }
    }
    __syncthreads();

    // ---- Heads: waves 0..3 -> m-frag = wave; j=0 mean, j=1 logstd ----
    float* lsf = (float*)yh;   // overlay: [64][16] floats (yh free)
    if (wave < 4) {
        f32x4 a0 = {0,0,0,0}, a1 = {0,0,0,0};
        const u16* wp0 = WhT + (size_t)l16 * 256 + quad * 8;          // mean rows 0..15
        const u16* wp1 = WhT + (size_t)(16 + l16) * 256 + quad * 8;   // logstd rows 16..31
        #pragma unroll
        for (int kt = 0; kt < 8; ++kt) {
            const int k0 = kt * 32;
            const bf16x8 af  = *(const bf16x8*)(ybf + SY(wave * 16 + l16, k0 + quad * 8));
            const bf16x8 bw0 = *(const bf16x8*)(wp0 + k0);
            const bf16x8 bw1 = *(const bf16x8*)(wp1 + k0);
            a0 = __builtin_amdgcn_mfma_f32_16x16x32_bf16(af, bw0, a0, 0, 0, 0);
            a1 = __builtin_amdgcn_mfma_f32_16x16x32_bf16(af, bw1, a1, 0, 0, 0);
        }
        if (l16 < 12) {
            const float bbm = bm[l16], bbs = bs[l16];
            #pragma unroll
            for (int r = 0; r < 4; ++r) {
                const int row = wave * 16 + quad * 4 + r;
                out[(size_t)(row0 + row) * 14 + l16] = a0[r] + bbm;
                lsf[row * 16 + l16] = fminf(fmaxf(a1[r] + bbs, -5.0f), 2.0f);
            }
        }
    }
    __syncthreads();
    if (tid < 64) {
        float s = 0.0f;
        #pragma unroll
        for (int q = 0; q < 12; ++q) s += lsf[tid * 16 + q];
        const float LOG2PI = 1.8378770664093453f;
        out[(size_t)(row0 + tid) * 14 + 12] = -s - 6.0f * LOG2PI;
        out[(size_t)(row0 + tid) * 14 + 13] =  s + 6.0f + 6.0f * LOG2PI;
    }
}

// ---------------------------------------------------------------------------
extern "C" void kernel_launch(void* const* d_in, const int* in_sizes, int n_in,
                              void* d_out, int out_size, void* d_ws, size_t ws_size,
                              hipStream_t stream) {
    (void)in_sizes; (void)n_in; (void)out_size; (void)ws_size;
    const float* x    = (const float*)d_in[0];
    const int*   done = (const int*)  d_in[1];
    const float* h0   = (const float*)d_in[2];
    const float* c0   = (const float*)d_in[3];
    const float* W_ih = (const float*)d_in[4];
    const float* W_hh = (const float*)d_in[5];
    const float* b_ih = (const float*)d_in[6];
    const float* b_hh = (const float*)d_in[7];
    const float* lng  = (const float*)d_in[8];
    const float* lnb  = (const float*)d_in[9];
    const float* W1   = (const float*)d_in[10];
    const float* b1   = (const float*)d_in[11];
    const float* W2   = (const float*)d_in[12];
    const float* b2   = (const float*)d_in[13];
    const float* Wm   = (const float*)d_in[14];
    const float* bm   = (const float*)d_in[15];
    const float* Ws   = (const float*)d_in[16];
    const float* bs   = (const float*)d_in[17];
    float* out = (float*)d_out;

    // workspace carve (~52 MB; ws_size >= 135 MB confirmed)
    unsigned char* p = (unsigned char*)d_ws;
    u16* hs    = (u16*)p;              p += (size_t)(T_ + 1) * BH_ * 2;
    u16* xpad  = (u16*)p;              p += (size_t)T_ * B_ * 64 * 2;
    u16* Wcat  = (u16*)p;              p += (size_t)1024 * KP_ * 2;
    u16* W1T   = (u16*)p;              p += (size_t)M1_ * H_ * 2;
    u16* W2T   = (u16*)p;              p += (size_t)M2_ * M1_ * 2;
    u16* WhT   = (u16*)p;              p += (size_t)32 * H_ * 2;
    unsigned* cnt = (unsigned*)p;      p += 256;

    prep_xpad<<<(T_ * B_ * 8) / 256, 256, 0, stream>>>(x, xpad, cnt);
    prep_weights<<<1824, 256, 0, stream>>>(W_ih, W_hh, W1, W2, Wm, Ws,
                                           Wcat, W1T, W2T, WhT);

    // 64 KB dynamic-LDS pad -> 84 KB/block -> exactly 1 block/CU (the fix).
    lstm_sync<<<GROUPS_ * SLICES_, 512, 65536, stream>>>(
        xpad, done, h0, c0, hs, Wcat, b_ih, b_hh, cnt);

    mlp_mfma64<<<(T_ * B_) / 64, 512, 0, stream>>>(
        hs + BH_, out, lng, lnb, W1T, b1, W2T, b2, WhT, bm, bs);
}

// Round 5
// 638.963 us; speedup vs baseline: 1.9931x; 1.3742x over previous
//
#include <hip/hip_runtime.h>
#include <hip/hip_bf16.h>
#include <math.h>

#define T_   64
#define B_   2048
#define OBS_ 48
#define H_   256
#define M1_  512
#define M2_  256
#define A_   12
#define BH_  (B_ * H_)
#define KP_  320   // padded K for scan: 64 (x, padded from 48) + 256 (h)
#define GROUPS_  128  // row groups (16 rows each)
#define SLICES_  2    // column-slice blocks per group (128 h-cols each)
#define RPB_     16   // rows per block

typedef unsigned short u16;
typedef unsigned long long u64;
typedef __attribute__((ext_vector_type(8))) short bf16x8;
typedef __attribute__((ext_vector_type(4))) float f32x4;

static __device__ __forceinline__ u16 f2b(float f) {
    __hip_bfloat16 h = __float2bfloat16(f);
    return *reinterpret_cast<u16*>(&h);
}
static __device__ __forceinline__ float b2f(u16 u) {
    union { unsigned u32v; float f; } v; v.u32v = ((unsigned)u) << 16; return v.f;
}
static __device__ __forceinline__ float sigm(float x) {
    return 1.0f / (1.0f + __expf(-x));
}
static __device__ __forceinline__ float tanh_fast(float x) {
    x = fminf(fmaxf(x, -15.0f), 15.0f);
    float e = __expf(2.0f * x);
    return (e - 1.0f) / (e + 1.0f);
}
static __device__ __forceinline__ float elu(float x) {
    return x > 0.0f ? x : (__expf(x) - 1.0f);
}

// ---------------------------------------------------------------------------
// Pre-pass kernels
// ---------------------------------------------------------------------------
__global__ void prep_xpad(const float* __restrict__ x, u16* __restrict__ xpad,
                          unsigned* __restrict__ cnt) {
    if (blockIdx.x == 0 && threadIdx.x < GROUPS_ * SLICES_) cnt[threadIdx.x] = 0;
    const int gid = blockIdx.x * 256 + threadIdx.x;   // T*B*8 threads
    const int r = gid >> 3, k0 = (gid & 7) * 8;
    u16 tmp[8];
    if (k0 < OBS_) {
        const float4 f0 = *(const float4*)(x + (size_t)r * OBS_ + k0);
        const float4 f1 = *(const float4*)(x + (size_t)r * OBS_ + k0 + 4);
        tmp[0] = f2b(f0.x); tmp[1] = f2b(f0.y); tmp[2] = f2b(f0.z); tmp[3] = f2b(f0.w);
        tmp[4] = f2b(f1.x); tmp[5] = f2b(f1.y); tmp[6] = f2b(f1.z); tmp[7] = f2b(f1.w);
    } else {
        #pragma unroll
        for (int i = 0; i < 8; ++i) tmp[i] = 0;
    }
    *(uint4*)(xpad + (size_t)gid * 8) = *(uint4*)tmp;
}

// Wcat permuted for lstm_sync2 (GROUPS=128/SLICES=2):
//   out-row = ((s*8 + w)*4 + g)*16 + jj  <-  src gate-row g*256 + (s*128 + w*16 + jj)
// Slice s owns h-cols [s*128, s*128+128). Wave w holds the 4 gates of h-cols
// [s*128+w*16, +16) as 4 separate register-resident B-frag sets -> lane-local
// gate fusion, zero weight memory traffic in the scan loop.
__global__ void prep_weights(const float* __restrict__ W_ih, const float* __restrict__ W_hh,
                             const float* __restrict__ W1,  const float* __restrict__ W2,
                             const float* __restrict__ Wm,  const float* __restrict__ Ws,
                             u16* __restrict__ Wcat, u16* __restrict__ W1T,
                             u16* __restrict__ W2T,  u16* __restrict__ WhT) {
    const int b = blockIdx.x, tid = threadIdx.x;
    if (b < 1024) {
        const int s = b >> 9, w = (b >> 6) & 7, g = (b >> 4) & 3, jj = b & 15;
        const int src = g * 256 + s * 128 + w * 16 + jj;
        for (int k = tid; k < KP_; k += 256) {
            float v;
            if (k < OBS_)    v = W_ih[src * OBS_ + k];
            else if (k < 64) v = 0.0f;
            else             v = W_hh[src * H_ + (k - 64)];
            Wcat[b * KP_ + k] = f2b(v);
        }
    } else if (b < 1536) {
        const int n = b - 1024;                       // W1T [512][256]
        W1T[n * 256 + tid] = f2b(W1[tid * M1_ + n]);
    } else if (b < 1792) {
        const int n = b - 1536;                       // W2T [256][512]
        W2T[n * 512 + tid]       = f2b(W2[tid * M2_ + n]);
        W2T[n * 512 + tid + 256] = f2b(W2[(tid + 256) * M2_ + n]);
    } else {
        const int n = b - 1792;                       // WhT [32][256]
        float v = 0.0f;
        if (n < 12)                 v = Wm[tid * A_ + n];
        else if (n >= 16 && n < 28) v = Ws[tid * A_ + (n - 16)];
        WhT[n * 256 + tid] = f2b(v);
    }
}

// ---------------------------------------------------------------------------
// Co-resident LSTM scan, round-4: minimal sync fan-in (pairs) + true 1 block/CU.
//  - 256 blocks (128 groups x 2 slices), 512 threads (8 waves).
//  - Weights: each wave's 4-gate x 10-ktile slice is register-resident
//    (Bs[4][10] bf16x8 = 160 VGPR). VGPR>128 => hardware caps the CU at
//    8 waves = EXACTLY 1 block/CU, 256 blocks over 256 CUs. No LDS trick.
//  - Per step, only the PARTNER's 4 KB h-half is read from global; the own
//    half is written straight into the LDS A-tile in the epilogue.
//  - Per-slice flag words (atomic store, no RMW): post own flag, THEN poll
//    partner (flag-before-poll => deadlock-free). Store->barrier->flag
//    ordering identical to the round-2/3 proven protocol.
//  - hs[t] slices are distinct per t and first-touch-per-reader, so plain
//    vectorized loads stay coherence-safe (no stale L2 lines possible).
// ---------------------------------------------------------------------------
#define ASM_(row, chunk) (a_sm + (size_t)(row) * 320 + (size_t)(((chunk) ^ ((row) & 7)) << 3))

__global__ __launch_bounds__(512, 2) void lstm_sync2(
    const u16*  __restrict__ xpad,   // [T][B][64] bf16
    const int*  __restrict__ done,   // [T][B]
    const float* __restrict__ h0,    // [B][256] fp32
    const float* __restrict__ c0,    // [B][256] fp32
    u16*        __restrict__ hs,     // [T+1][B][256] bf16; slices 1..T written
    const u16*  __restrict__ Wcat,   // [1024 permuted][320] bf16
    const float* __restrict__ b_ih,
    const float* __restrict__ b_hh,
    unsigned*   __restrict__ cnt)    // [256] per-slice step flags (zeroed by prep)
{
    __shared__ u16 a_sm[RPB_ * 320];   // 10 KB

    const int tid  = threadIdx.x;
    const int lane = tid & 63;
    const int w    = tid >> 6;               // wave 0..7 -> h-colfrag
    const int quad = lane >> 4, l16 = lane & 15;
    const int grp  = blockIdx.x >> 1;        // 0..127
    const int s    = blockIdx.x & 1;         // 0..1
    const int b0   = grp * RPB_;
    const int j    = s * 128 + w * 16 + l16; // this lane's h column (0..255)
    const int pc0  = (1 - s) * 128;          // partner column base

    // ---- fused biases: 4 gates of column j ----
    float bsum[4];
    #pragma unroll
    for (int g = 0; g < 4; ++g) bsum[g] = b_ih[g * 256 + j] + b_hh[g * 256 + j];

    // ---- persistent c state (pre-masked with done[0]) ----
    float cst[4];
    #pragma unroll
    for (int r = 0; r < 4; ++r) {
        const int row = b0 + quad * 4 + r;
        cst[r] = done[row] ? 0.0f : c0[(size_t)row * H_ + j];
    }

    // ---- this wave's weight slice, register-resident: 4 gates x 10 kt ----
    bf16x8 Bs[4][10];
    #pragma unroll
    for (int g = 0; g < 4; ++g) {
        const u16* wp = Wcat + (size_t)(((s * 8 + w) * 4 + g) * 16 + l16) * KP_ + quad * 8;
        #pragma unroll
        for (int kt = 0; kt < 10; ++kt)
            Bs[g][kt] = *(const bf16x8*)(wp + kt * 32);
    }

    // ---- pre-loop: stage x(0) and h0 (masked by done[0]) ----
    if ((tid & 3) == 0) {
        const int idx = tid >> 2, row = idx >> 3, seg = idx & 7;
        *(uint4*)ASM_(row, seg) =
            *(const uint4*)(xpad + (size_t)(b0 + row) * 64 + seg * 8);
    }
    {
        const int row = tid >> 5, c8 = tid & 31;
        const int dn = done[b0 + row];
        const float* hr = h0 + (size_t)(b0 + row) * H_ + c8 * 8;
        u16 tmp[8];
        #pragma unroll
        for (int e = 0; e < 8; ++e) tmp[e] = dn ? (u16)0 : f2b(hr[e]);
        *(uint4*)ASM_(row, 8 + c8) = *(uint4*)tmp;
    }
    __syncthreads();

    // ================= 64-step scan =================
    for (int t = 0; t < T_; ++t) {
        // ---- GEMM: 10 ds_read + 40 MFMA per wave; B entirely from VGPRs ----
        f32x4 acc[4];
        #pragma unroll
        for (int g = 0; g < 4; ++g) acc[g] = (f32x4){0, 0, 0, 0};
        #pragma unroll
        for (int kt = 0; kt < 10; ++kt) {
            const bf16x8 af = *(const bf16x8*)ASM_(l16, kt * 4 + quad);
            #pragma unroll
            for (int g = 0; g < 4; ++g)
                acc[g] = __builtin_amdgcn_mfma_f32_16x16x32_bf16(af, Bs[g][kt], acc[g], 0, 0, 0);
        }
        __syncthreads();   // all waves done reading the A-tile

        // ---- epilogue: gate fusion; own h-half -> LDS + hs[t+1]; x(t+1) stage ----
        u16* hs1 = hs + (size_t)(t + 1) * BH_;
        #pragma unroll
        for (int r = 0; r < 4; ++r) {
            const int rowl = quad * 4 + r;
            const int rowg = b0 + rowl;
            const float gi = acc[0][r] + bsum[0];
            const float gf = acc[1][r] + bsum[1];
            const float gg = acc[2][r] + bsum[2];
            const float go = acc[3][r] + bsum[3];
            const float cn = sigm(gf) * cst[r] + sigm(gi) * tanh_fast(gg);
            const float h  = sigm(go) * tanh_fast(cn);
            const float kp = (t + 1 < T_)
                ? (done[(size_t)(t + 1) * B_ + rowg] ? 0.0f : 1.0f) : 1.0f;
            cst[r] = cn * kp;                      // pre-mask c for step t+1
            const int e = 64 + j;                  // own half into LDS, masked
            *(ASM_(rowl, e >> 3) + (e & 7)) = f2b(h * kp);
            const unsigned hb = (unsigned)f2b(h);  // unmasked history to global
            const unsigned ob = (unsigned)__shfl_xor((int)hb, 1);
            if ((l16 & 1) == 0) {                  // pack (j, j+1) -> one u32 store
                const unsigned val = hb | (ob << 16);
                __hip_atomic_store((unsigned*)(hs1 + (size_t)rowg * H_ + (j & ~1)), val,
                                   __ATOMIC_RELAXED, __HIP_MEMORY_SCOPE_AGENT);
            }
        }
        if (t + 1 < T_ && (tid & 3) == 0) {        // x(t+1), hidden in this phase
            const int idx = tid >> 2, row = idx >> 3, seg = idx & 7;
            *(uint4*)ASM_(row, seg) =
                *(const uint4*)(xpad + ((size_t)(t + 1) * B_ + b0 + row) * 64 + seg * 8);
        }
        __syncthreads();   // drains vmcnt (stores at coherence point) + LDS order

        if (t + 1 < T_) {
            // ---- post own flag FIRST, then poll partner (deadlock-free) ----
            if (tid == 0) {
                __hip_atomic_store(&cnt[blockIdx.x], (unsigned)(t + 1),
                                   __ATOMIC_RELAXED, __HIP_MEMORY_SCOPE_AGENT);
                int guard = 0;
                while (__hip_atomic_load(&cnt[blockIdx.x ^ 1], __ATOMIC_RELAXED,
                                         __HIP_MEMORY_SCOPE_AGENT) < (unsigned)(t + 1)) {
                    __builtin_amdgcn_s_sleep(1);
                    if (++guard > (1 << 24)) break;   // deadlock -> wrong answer, not hang
                }
            }
            __syncthreads();

            // ---- stage partner h(t+1) half (4 KB), masked by done[t+1] ----
            if (tid < 256) {
                const int row = tid >> 4, q = tid & 15;
                const int dn = done[(size_t)(t + 1) * B_ + b0 + row];
                const int pc = pc0 + q * 8;
                uint4 hv = *(const uint4*)(hs1 + (size_t)(b0 + row) * H_ + pc);
                if (dn) hv = make_uint4(0u, 0u, 0u, 0u);
                *(uint4*)ASM_(row, 8 + ((pc0 >> 3) + q)) = hv;
            }
            __syncthreads();
        }
    }
}

// ---------------------------------------------------------------------------
// MLP v2: 64 rows/block, 512 threads, two-phase y1. Round-5 fix: nontemporal
// hs loads done as scalar u64 (vector types rejected by the builtin) so the
// 64 MB h-stream doesn't evict L2-resident W1T/W2T weight panels.
// ---------------------------------------------------------------------------
#define SY(row, col) ((size_t)(row) * 256 + ((((col) >> 3) ^ ((row) & 7)) << 3) + ((col) & 7))

__global__ __launch_bounds__(512, 4) void mlp_mfma64(
    const u16*  __restrict__ hs,    // [nrows][256] bf16
    float*      __restrict__ out,   // [nrows][14]
    const float* __restrict__ lng, const float* __restrict__ lnb,
    const u16*  __restrict__ W1T, const float* __restrict__ b1,
    const u16*  __restrict__ W2T, const float* __restrict__ b2,
    const u16*  __restrict__ WhT,
    const float* __restrict__ bm, const float* __restrict__ bs)
{
    __shared__ u16 ybf[64 * 256];   // 32 KB swizzled: LN output, later y2
    __shared__ u16 yh [64 * 256];   // 32 KB swizzled: y1 column-half; later ls overlay

    const int tid  = threadIdx.x;
    const int lane = tid & 63;
    const int wave = tid >> 6;        // 0..7
    const int quad = lane >> 4, l16 = lane & 15;
    const int row0 = blockIdx.x * 64;

    // ---- LayerNorm: wave w -> rows w*8..w*8+7; lane holds 4 cols ----
    {
        const float4 gv = *(const float4*)(lng + lane * 4);
        const float4 bv = *(const float4*)(lnb + lane * 4);
        #pragma unroll
        for (int rr = 0; rr < 8; ++rr) {
            const int r = wave * 8 + rr;
            const u64 hv8 = __builtin_nontemporal_load(
                (const u64*)(hs + (size_t)(row0 + r) * H_ + lane * 4));
            const u16 h0v = (u16)(hv8 & 0xffff), h1v = (u16)((hv8 >> 16) & 0xffff);
            const u16 h2v = (u16)((hv8 >> 32) & 0xffff), h3v = (u16)(hv8 >> 48);
            const float v0 = b2f(h0v), v1 = b2f(h1v), v2 = b2f(h2v), v3 = b2f(h3v);
            float s  = v0 + v1 + v2 + v3;
            float ss = v0 * v0 + v1 * v1 + v2 * v2 + v3 * v3;
            #pragma unroll
            for (int off = 32; off > 0; off >>= 1) {
                s  += __shfl_down(s,  off);
                ss += __shfl_down(ss, off);
            }
            s = __shfl(s, 0); ss = __shfl(ss, 0);
            const float mu   = s * (1.0f / 256.0f);
            const float rstd = rsqrtf(ss * (1.0f / 256.0f) - mu * mu + 1e-5f);
            ushort4 o;
            o.x = f2b((v0 - mu) * rstd * gv.x + bv.x);
            o.y = f2b((v1 - mu) * rstd * gv.y + bv.y);
            o.z = f2b((v2 - mu) * rstd * gv.z + bv.z);
            o.w = f2b((v3 - mu) * rstd * gv.w + bv.w);
            *(ushort4*)(ybf + SY(r, lane * 4)) = o;
        }
    }
    __syncthreads();

    // ---- L2 partial accumulators: live across both phases ----
    f32x4 acc2[4][2];
    #pragma unroll
    for (int m = 0; m < 4; ++m)
        #pragma unroll
        for (int j = 0; j < 2; ++j) acc2[m][j] = (f32x4){0,0,0,0};

    #pragma unroll
    for (int ph = 0; ph < 2; ++ph) {
        // ---- L1 phase: y1 cols [ph*256, ph*256+256); wave n-slice 32 cols ----
        {
            f32x4 acc[4][2];
            #pragma unroll
            for (int m = 0; m < 4; ++m)
                #pragma unroll
                for (int j = 0; j < 2; ++j) acc[m][j] = (f32x4){0,0,0,0};
            const int n0 = ph * 256 + wave * 32;
            const u16* wp0 = W1T + (size_t)(n0 + l16) * 256 + quad * 8;
            const u16* wp1 = W1T + (size_t)(n0 + 16 + l16) * 256 + quad * 8;
            #pragma unroll
            for (int kt = 0; kt < 8; ++kt) {
                const int k0 = kt * 32;
                const bf16x8 bw0 = *(const bf16x8*)(wp0 + k0);
                const bf16x8 bw1 = *(const bf16x8*)(wp1 + k0);
                #pragma unroll
                for (int m = 0; m < 4; ++m) {
                    const bf16x8 af = *(const bf16x8*)(ybf + SY(m * 16 + l16, k0 + quad * 8));
                    acc[m][0] = __builtin_amdgcn_mfma_f32_16x16x32_bf16(af, bw0, acc[m][0], 0, 0, 0);
                    acc[m][1] = __builtin_amdgcn_mfma_f32_16x16x32_bf16(af, bw1, acc[m][1], 0, 0, 0);
                }
            }
            const float bb0 = b1[n0 + l16], bb1 = b1[n0 + 16 + l16];
            __syncthreads();   // yh free (prev phase consumed / first use)
            #pragma unroll
            for (int m = 0; m < 4; ++m)
                #pragma unroll
                for (int r = 0; r < 4; ++r) {
                    const int row = m * 16 + quad * 4 + r;
                    yh[SY(row, wave * 32 + l16)]      = f2b(elu(acc[m][0][r] + bb0));
                    yh[SY(row, wave * 32 + 16 + l16)] = f2b(elu(acc[m][1][r] + bb1));
                }
        }
        __syncthreads();

        // ---- L2 partial: K in [ph*256, ph*256+256); wave n-slice 32 cols ----
        {
            const int n0 = wave * 32;
            const u16* wp0 = W2T + (size_t)(n0 + l16) * 512 + ph * 256 + quad * 8;
            const u16* wp1 = W2T + (size_t)(n0 + 16 + l16) * 512 + ph * 256 + quad * 8;
            #pragma unroll
            for (int kt = 0; kt < 8; ++kt) {
                const int k0 = kt * 32;
                const bf16x8 bw0 = *(const bf16x8*)(wp0 + k0);
                const bf16x8 bw1 = *(const bf16x8*)(wp1 + k0);
                #pragma unroll
                for (int m = 0; m < 4; ++m) {
                    const bf16x8 af = *(const bf16x8*)(yh + SY(m * 16 + l16, k0 + quad * 8));
                    acc2[m][0] = __builtin_amdgcn_mfma_f32_16x16x32_bf16(af, bw0, acc2[m][0], 0, 0, 0);
                    acc2[m][1] = __builtin_amdgcn_mfma_f32_16x16x32_bf16(af, bw1, acc2[m][1], 0, 0, 0);
                }
            }
        }
        __syncthreads();
    }

    // ---- y2 = elu(acc2 + b2) -> ybf (LN data fully consumed) ----
    {
        const float bb0 = b2[wave * 32 + l16], bb1 = b2[wave * 32 + 16 + l16];
        #pragma unroll
        for (int m = 0; m < 4; ++m)
            #pragma unroll
            for (int r = 0; r < 4; ++r) {
                const int row = m * 16 + quad * 4 + r;
                ybf[SY(row, wave * 32 + l16)]      = f2b(elu(acc2[m][0][r] + bb0));
                ybf[SY(row, wave * 32 + 16 + l16)] = f2b(elu(acc2[m][1][r] + bb1));
            }
    }
    __syncthreads();

    // ---- Heads: waves 0..3 -> m-frag = wave; j=0 mean, j=1 logstd ----
    float* lsf = (float*)yh;   // overlay: [64][16] floats (yh free)
    if (wave < 4) {
        f32x4 a0 = {0,0,0,0}, a1 = {0,0,0,0};
        const u16* wp0 = WhT + (size_t)l16 * 256 + quad * 8;          // mean rows 0..15
        const u16* wp1 = WhT + (size_t)(16 + l16) * 256 + quad * 8;   // logstd rows 16..31
        #pragma unroll
        for (int kt = 0; kt < 8; ++kt) {
            const int k0 = kt * 32;
            const bf16x8 af  = *(const bf16x8*)(ybf + SY(wave * 16 + l16, k0 + quad * 8));
            const bf16x8 bw0 = *(const bf16x8*)(wp0 + k0);
            const bf16x8 bw1 = *(const bf16x8*)(wp1 + k0);
            a0 = __builtin_amdgcn_mfma_f32_16x16x32_bf16(af, bw0, a0, 0, 0, 0);
            a1 = __builtin_amdgcn_mfma_f32_16x16x32_bf16(af, bw1, a1, 0, 0, 0);
        }
        if (l16 < 12) {
            const float bbm = bm[l16], bbs = bs[l16];
            #pragma unroll
            for (int r = 0; r < 4; ++r) {
                const int row = wave * 16 + quad * 4 + r;
                out[(size_t)(row0 + row) * 14 + l16] = a0[r] + bbm;
                lsf[row * 16 + l16] = fminf(fmaxf(a1[r] + bbs, -5.0f), 2.0f);
            }
        }
    }
    __syncthreads();
    if (tid < 64) {
        float s = 0.0f;
        #pragma unroll
        for (int q = 0; q < 12; ++q) s += lsf[tid * 16 + q];
        const float LOG2PI = 1.8378770664093453f;
        out[(size_t)(row0 + tid) * 14 + 12] = -s - 6.0f * LOG2PI;
        out[(size_t)(row0 + tid) * 14 + 13] =  s + 6.0f + 6.0f * LOG2PI;
    }
}

// ---------------------------------------------------------------------------
extern "C" void kernel_launch(void* const* d_in, const int* in_sizes, int n_in,
                              void* d_out, int out_size, void* d_ws, size_t ws_size,
                              hipStream_t stream) {
    (void)in_sizes; (void)n_in; (void)out_size; (void)ws_size;
    const float* x    = (const float*)d_in[0];
    const int*   done = (const int*)  d_in[1];
    const float* h0   = (const float*)d_in[2];
    const float* c0   = (const float*)d_in[3];
    const float* W_ih = (const float*)d_in[4];
    const float* W_hh = (const float*)d_in[5];
    const float* b_ih = (const float*)d_in[6];
    const float* b_hh = (const float*)d_in[7];
    const float* lng  = (const float*)d_in[8];
    const float* lnb  = (const float*)d_in[9];
    const float* W1   = (const float*)d_in[10];
    const float* b1   = (const float*)d_in[11];
    const float* W2   = (const float*)d_in[12];
    const float* b2   = (const float*)d_in[13];
    const float* Wm   = (const float*)d_in[14];
    const float* bm   = (const float*)d_in[15];
    const float* Ws   = (const float*)d_in[16];
    const float* bs   = (const float*)d_in[17];
    float* out = (float*)d_out;

    // workspace carve (~52 MB; ws_size >= 135 MB confirmed)
    unsigned char* p = (unsigned char*)d_ws;
    u16* hs    = (u16*)p;              p += (size_t)(T_ + 1) * BH_ * 2;
    u16* xpad  = (u16*)p;              p += (size_t)T_ * B_ * 64 * 2;
    u16* Wcat  = (u16*)p;              p += (size_t)1024 * KP_ * 2;
    u16* W1T   = (u16*)p;              p += (size_t)M1_ * H_ * 2;
    u16* W2T   = (u16*)p;              p += (size_t)M2_ * M1_ * 2;
    u16* WhT   = (u16*)p;              p += (size_t)32 * H_ * 2;
    unsigned* cnt = (unsigned*)p;      p += 1024;

    prep_xpad<<<(T_ * B_ * 8) / 256, 256, 0, stream>>>(x, xpad, cnt);
    prep_weights<<<1824, 256, 0, stream>>>(W_ih, W_hh, W1, W2, Wm, Ws,
                                           Wcat, W1T, W2T, WhT);

    lstm_sync2<<<GROUPS_ * SLICES_, 512, 0, stream>>>(
        xpad, done, h0, c0, hs, Wcat, b_ih, b_hh, cnt);

    mlp_mfma64<<<(T_ * B_) / 64, 512, 0, stream>>>(
        hs + BH_, out, lng, lnb, W1T, b1, W2T, b2, WhT, bm, bs);
}